// Round 19
// baseline (117.915 us; speedup 1.0000x reference)
//
#include <hip/hip_runtime.h>
#include <cmath>

// SSIM stability loss: 1 - mean(SSIM(x,y)), 11x11 Gaussian (sigma=1.5), zero SAME
// padding, fp32, 32 x 1 x 512 x 512.
//
// R35 = final: R26/ssim8 exact (proven best, 42-44us kernel). R34's 2-col
// variant was selected by the spill-hedge and regressed (69-75us, VALUBusy
// 25%, bank conflicts 2x): third independent refutation of 2-col/thread
// (R20 block-tile 1blk, R21 block-tile 2blk, R34 wave-private). Exploration
// complete -- all axes bounded by valid experiments:
//   TLP: 2 waves/SIMD is the reachable max (compiler 64-VGPR wall at 1024
//        thr even with waves_per_eu(4,4) [R24/R31/R33]; multi-block
//        co-residency never materializes [R16/R29]).
//   Barriers: barrier-free wave-private tiles are best (R23/R26 vs R25).
//   ILP/MLP/wait-density/chain-depth: all neutral (R17/R22/R27).
//   Work: sum/diff channels -20% -> -20% time (R19); further fusion
//        (2-col) trades issue-window quality and loses (R20/R21/R34).
// Plateau: VALU ~18us + LDS ~12-18us, serializing at 2 waves/SIMD; both
// pipes ~44% busy, sum ~90%. This is the structural limit of the
// decomposition on this compiler/dispatcher.
//
// Structure: one 512-thr block/CU (grid (8,32)=256); 8 barrier-free
// independent waves, each owning a 64-col strip x 64-row band with a
// private double-buffered 11-row LDS tile (8 x 14080 B dynamic); in-order
// per-wave DS is the only sync. Inner loop: unscaled sum/diff channels
// u=x+y, v=x-y + squares (2C1/2C2 algebra); 6 aligned ds_read_b128/row;
// parity-folded 12-tap weight vector; 11-deep circular history; fp64
// atomic finish.

#define IMG   512
#define BROWS 64
#define NHROW (BROWS + 10)   // 74 H-rows per band
#define NCHUNK 7             // ceil(74/11)
#define CHR   11             // rows per LDS chunk (== history depth)
#define WQUADS 20            // float4 col-quads staged per row per wave (80 cols)
#define WUNITS 40            // v4f units per staged row per wave
#define NQ (CHR * WQUADS)    // 220 quads per chunk per wave
#define WAVE_LDS (2 * CHR * WUNITS)        // v4f units per wave (dbuf)
#define LDS_BYTES (8 * WAVE_LDS * 16)      // 112640
#define NBLOCKS 256
#define NPIX  8388608.0

typedef float v2f __attribute__((ext_vector_type(2)));
typedef float v4f __attribute__((ext_vector_type(4)));

struct GaussW { float w[11]; };

__global__ __launch_bounds__(512, 1)
void ssim_stream_kernel(const float* __restrict__ x, const float* __restrict__ y,
                        double* __restrict__ acc_ws, unsigned long long* __restrict__ ctr,
                        float* __restrict__ out, GaussW gw) {
    extern __shared__ v4f dsm[];        // [8 waves][2 bufs][CHR][WUNITS]
    __shared__ float wavesum[8];

    const int tid  = threadIdx.x;
    const int w    = tid >> 6;          // wave id 0..7, owns a 64-col strip
    const int lane = tid & 63;
    const int c0 = w * 64;              // strip base col (block covers all 512)
    const int r0 = blockIdx.x * BROWS;
    const size_t img_off = (size_t)blockIdx.y * (IMG * IMG);
    const float* __restrict__ xb = x + img_off;
    const float* __restrict__ yb = y + img_off;

    v4f (*wtile)[CHR][WUNITS] =
        reinterpret_cast<v4f (*)[CHR][WUNITS]>(dsm + (size_t)w * WAVE_LDS);

    // lane's output col = c0 + lane; taps at staged cols lane+3 .. lane+13
    // (stage base c0-8). Aligned 6 x b128 window starting at unit ub.
    const int ub = (lane + 3) >> 1;
    const int p  = (lane + 3) & 1;      // parity: tap k sits at window pos p+k

    // 12-tap per-lane weight vector: window pos m covers staged col 2*ub + m;
    // logical tap k = m - p, so wv2[m] = w[m-p] (0 outside [0,10]).
    v2f wv2[12];
    #pragma unroll
    for (int m = 0; m < 12; ++m) {
        float lo = (m <= 10) ? gw.w[m] : 0.f;       // p == 0
        float hi = (m >= 1) ? gw.w[m - 1] : 0.f;    // p == 1
        float wm = p ? hi : lo;
        wv2[m][0] = wm; wv2[m][1] = wm;
    }
    v2f wp[11];                          // vertical weights (parity-free)
    #pragma unroll
    for (int k = 0; k < 11; ++k) { wp[k][0] = gw.w[k]; wp[k][1] = gw.w[k]; }

    float4 sxr[4], syr[4];   // staged regs for next chunk (4 iters x 64 lanes >= 220)

    auto load_chunk = [&](int c) {
        #pragma unroll
        for (int it = 0; it < 4; ++it) {
            int idx = lane + it * 64;
            int row = idx / WQUADS;
            int q   = idx - row * WQUADS;
            int gr = r0 - 5 + c * CHR + row;       // global image row
            int gc = c0 - 8 + q * 4;               // global col of float4 (16B aligned)
            float4 vx = make_float4(0.f, 0.f, 0.f, 0.f);
            float4 vy = vx;
            if (idx < NQ && (unsigned)gr < IMG && (unsigned)gc < IMG) {
                const float* px = xb + (size_t)gr * IMG + gc;
                const float* py = yb + (size_t)gr * IMG + gc;
                vx = *(const float4*)px;
                vy = *(const float4*)py;
            }
            sxr[it] = vx; syr[it] = vy;
        }
    };
    // stage as u=x+y, v=x-y (unscaled; zero padding maps to zero: linear)
    auto store_chunk = [&](int b) {
        #pragma unroll
        for (int it = 0; it < 4; ++it) {
            int idx = lane + it * 64;
            if (idx < NQ) {
                int row = idx / WQUADS;
                int q   = idx - row * WQUADS;
                const float4 vx = sxr[it], vy = syr[it];
                wtile[b][row][q * 2]     = (v4f){vx.x + vy.x, vx.x - vy.x,
                                                 vx.y + vy.y, vx.y - vy.y};
                wtile[b][row][q * 2 + 1] = (v4f){vx.z + vy.z, vx.z - vy.z,
                                                 vx.w + vy.w, vx.w - vy.w};
            }
        }
    };

    v2f histL[11];     // (hu, hv)     -- linear channel H-conv results
    v2f histQ[11];     // (huu, hvv)   -- quadratic channel H-conv results
    float lsum = 0.f;
    const float C1x2 = 2e-4f, C2x2 = 1.8e-3f;   // 2*C1, 2*C2 (unscaled algebra)

    load_chunk(0);
    store_chunk(0);
    // no barrier: DS ops of one wave complete in order; compiler inserts the
    // lgkmcnt before the first dependent ds_read use.

    #pragma unroll 1
    for (int c = 0; c < NCHUNK; ++c) {      // 7 chunks x 11 rows = 77 >= 74
        const int b = c & 1;
        if (c < NCHUNK - 1) load_chunk(c + 1);  // global loads overlap chunk-c compute

        #pragma unroll
        for (int s = 0; s < CHR; ++s) {     // H-row m = 11c + s; hist slot = s
            if (!(c == NCHUNK - 1 && s >= NHROW - (NCHUNK - 1) * CHR)) {   // m < 74
                v4f w6[6];
                #pragma unroll
                for (int i = 0; i < 6; ++i) w6[i] = wtile[b][s][ub + i];

                // --- horizontal conv: 12 taps, 3 packed ops each ---
                v2f hL = (v2f){0.f, 0.f};
                v2f hQ = (v2f){0.f, 0.f};
                #pragma unroll
                for (int m = 0; m < 12; ++m) {
                    v2f t = (m & 1) ? w6[m >> 1].zw : w6[m >> 1].xy;
                    hL = __builtin_elementwise_fma(wv2[m], t, hL);   // v_pk_fma_f32
                    v2f q = t * t;                                   // v_pk_mul_f32
                    hQ = __builtin_elementwise_fma(wv2[m], q, hQ);   // v_pk_fma_f32
                }
                histL[s] = hL; histQ[s] = hQ;

                // --- output row (11c + s - 10) completes now ---
                if (c > 0 || s == 10) {
                    v2f aL = (v2f){0.f, 0.f};
                    v2f aQ = (v2f){0.f, 0.f};
                    #pragma unroll
                    for (int j = 0; j < 11; ++j) {
                        const int sl = (s + 1 + j) % 11;   // static per (s,j)
                        aL = __builtin_elementwise_fma(wp[j], histL[sl], aL);
                        aQ = __builtin_elementwise_fma(wp[j], histQ[sl], aQ);
                    }
                    float a = aL[0] * aL[0], bq = aL[1] * aL[1];
                    float dm = a - bq;             // = 4 mx my
                    float sm = a + bq;             // = 2(mx^2 + my^2)
                    float num = (dm + C1x2) * ((aQ[0] - aQ[1]) - dm + C2x2);
                    float den = (sm + C1x2) * ((aQ[0] + aQ[1]) - sm + C2x2);
                    lsum += num * __builtin_amdgcn_rcpf(den);
                }
            }
        }

        // write next chunk into this wave's OTHER buffer -- no barrier needed,
        // reads of buffer b above are older DS ops of the same wave (in-order).
        if (c < NCHUNK - 1) store_chunk(b ^ 1);
    }

    // ---- reduction: wave shuffle -> LDS -> block partial -> fp64 atomic ----
    #pragma unroll
    for (int off = 32; off > 0; off >>= 1)
        lsum += __shfl_down(lsum, off, 64);
    if (lane == 0) wavesum[w] = lsum;
    __syncthreads();
    if (tid == 0) {
        float bs = 0.f;
        #pragma unroll
        for (int i = 0; i < 8; ++i) bs += wavesum[i];
        atomicAdd(acc_ws, (double)bs);
        __threadfence();
        unsigned long long old = atomicAdd(ctr, 1ull);
        if (old == (unsigned long long)(NBLOCKS - 1)) {
            __threadfence();
            double total = atomicAdd(acc_ws, 0.0);   // atomic RMW sees all prior adds
            out[0] = (float)(1.0 - total / NPIX);
        }
    }
}

extern "C" void kernel_launch(void* const* d_in, const int* in_sizes, int n_in,
                              void* d_out, int out_size, void* d_ws, size_t ws_size,
                              hipStream_t stream) {
    const float* x = (const float*)d_in[0];   // heatmap_clean
    const float* y = (const float*)d_in[1];   // heatmap_adv
    float* out = (float*)d_out;
    double* acc = (double*)d_ws;
    unsigned long long* ctr = (unsigned long long*)((char*)d_ws + 8);

    // allow > 64 KB dynamic LDS (host-side attribute, graph-capture safe)
    static bool attr_set = false;
    if (!attr_set) {
        hipFuncSetAttribute(reinterpret_cast<const void*>(ssim_stream_kernel),
                            hipFuncAttributeMaxDynamicSharedMemorySize, LDS_BYTES);
        attr_set = true;
    }

    // zero the 16B of accumulator+counter state (capture-safe async memset)
    hipMemsetAsync(d_ws, 0, 16, stream);

    GaussW gw;
    double g[11], s = 0.0;
    for (int i = 0; i < 11; ++i) { double d = i - 5; g[i] = exp(-(d * d) / 4.5); s += g[i]; }
    for (int i = 0; i < 11; ++i) gw.w[i] = (float)(g[i] / s);

    dim3 grid(IMG / BROWS, 32);   // (8, 32) = 256 blocks = 1/CU, 8 indep waves forced
    ssim_stream_kernel<<<grid, 512, LDS_BYTES, stream>>>(x, y, acc, ctr, out, gw);
}